// Round 12
// baseline (209.324 us; speedup 1.0000x reference)
//
#include <hip/hip_runtime.h>
#include <hip/hip_bf16.h>

#define BZn 32
#define CAPn 134
#define SEQn 144
#define INVn 16
#define ESP 1072
#define EFT 64

// ws layout (bytes):
// 0     : g_rp   135 ints
// 540   : g_col  1072 ints
// 4828  : g_inv  134 floats
// 5376  : uB     512 bf16 (1024 B)  — H1 = AdjW@F1 fragments, K=32 pad
// 6400  : vB     512 bf16           — F1 fragments, K=32 pad
// 7424  : spB2   512 bf16           — [Wl@F0 ; Wr@F0] fragments (K=32)
// 8448  : biasf  32 floats          — bias_i[16] (bl@F0+fcb), cs[16] (colsum F1)
// 8704  : convA2 2048 bf16 (4096 B) — conv weights ⊗ F2, A-fragments
// 12800 : featB  41472 bf16 (82944) — [fWl;fWr] B-fragments (K=288)
// end 95744

typedef __attribute__((ext_vector_type(8))) short bf16x8;
typedef __attribute__((ext_vector_type(4))) short short4v;
typedef __attribute__((ext_vector_type(4))) float f32x4;

#define MFMA(a, b, c) __builtin_amdgcn_mfma_f32_16x16x32_bf16(a, b, c, 0, 0, 0)

__device__ __forceinline__ unsigned short f2bf(float f) {
    union { float f; unsigned u; } v; v.f = f;
    unsigned r = v.u + 0x7fff + ((v.u >> 16) & 1);
    return (unsigned short)(r >> 16);
}
__device__ __forceinline__ unsigned pk2(float a, float b) {
    float2 v; v.x = a; v.y = b;
    union { __hip_bfloat162 h; unsigned u; } c;
    c.h = __float22bfloat162_rn(v);
    return c.u;
}
__device__ __forceinline__ short4v pack4(f32x4 v) {
    union { unsigned u[2]; short4v s; } r;
    r.u[0] = pk2(v[0], v[1]);
    r.u[1] = pk2(v[2], v[3]);
    return r.s;
}

// R13 prep (kept): job-parallel, 12 blocks. b0=CSR, b1=combos+biasf,
// b2=convA2, b3..b11=featB slabs. Critical path = max(job).
__global__ __launch_bounds__(256) void prep_kernel(
    const int* __restrict__ ge, const int* __restrict__ fe,
    const float* __restrict__ Wl,  const float* __restrict__ Wr,
    const float* __restrict__ fWl, const float* __restrict__ fWr,
    const float* __restrict__ w1,  const float* __restrict__ w2,
    const float* __restrict__ fcw, const float* __restrict__ bl,
    const float* __restrict__ fcb,
    int* __restrict__ ws)
{
    int t = threadIdx.x;
    char* wsb = (char*)ws;
    unsigned short* uB     = (unsigned short*)(wsb + 5376);
    unsigned short* vB     = (unsigned short*)(wsb + 6400);
    unsigned short* spB2   = (unsigned short*)(wsb + 7424);
    float*          biasf  = (float*)(wsb + 8448);
    unsigned short* convA2 = (unsigned short*)(wsb + 8704);
    unsigned short* featB  = (unsigned short*)(wsb + 12800);

    if (blockIdx.x == 0) {
        int* g_rp  = ws;
        int* g_col = ws + 135;
        float* g_inv = (float*)(ws + 1207);
        __shared__ int cnt[CAPn], off[CAPn];
        for (int c0 = t; c0 < CAPn; c0 += 256) cnt[c0] = 0;
        __syncthreads();
        for (int e = t; e < ESP; e += 256) atomicAdd(&cnt[ge[ESP + e]], 1);
        __syncthreads();
        if (t == 0) {
            int run = 0;
            for (int c0 = 0; c0 < CAPn; c0++) {
                off[c0] = run; g_rp[c0] = run;
                g_inv[c0] = 1.0f / fmaxf((float)cnt[c0], 1.0f);
                run += cnt[c0];
            }
            g_rp[CAPn] = run;
        }
        __syncthreads();
        for (int c0 = t; c0 < CAPn; c0 += 256) cnt[c0] = 0;
        __syncthreads();
        for (int e = t; e < ESP; e += 256) {
            int d = ge[ESP + e];
            int p = off[d] + atomicAdd(&cnt[d], 1);
            g_col[p] = ge[e];
        }
    } else if (blockIdx.x == 1) {
        // sw: fcw@0(768) Wl@768(256) Wr@1024(256) bl@1280(16) fcb@1296(16)
        __shared__ float sw[1312];
        __shared__ int fm[256];
        __shared__ float finv[16];
        for (int u = t; u < 768; u += 256) sw[u] = fcw[u];
        if (t < 256) sw[768 + t]  = Wl[t];
        if (t < 256) sw[1024 + t] = Wr[t];
        if (t < 16)  sw[1280 + t] = bl[t];
        if (t < 16)  sw[1296 + t] = fcb[t];
        fm[t] = 0;
        __syncthreads();
        if (t < EFT) atomicAdd(&fm[fe[t] * 16 + fe[EFT + t]], 1);
        __syncthreads();
        if (t < 16) {
            int dg = 0;
            for (int j = 0; j < 16; j++) dg += fm[j * 16 + t];
            finv[t] = 1.0f / fmaxf((float)dg, 1.0f);
        }
        __syncthreads();
        for (int u = t; u < 512; u += 256) {
            int l = u >> 3, j = u & 7, k = (l >> 4) * 8 + j, ip = l & 15;
            float vu = 0.f, vv = 0.f, vs = 0.f;
            if (k < 16) {
                for (int i = 0; i < 16; i++)
                    vu += (float)fm[k * 16 + i] * finv[i] * sw[(16 + i) * 16 + ip];
                vv = sw[(16 + k) * 16 + ip];
                for (int i = 0; i < 16; i++) vs += sw[768 + k * 16 + i] * sw[i * 16 + ip];
            } else {
                for (int i = 0; i < 16; i++) vs += sw[1024 + (k - 16) * 16 + i] * sw[i * 16 + ip];
            }
            uB[u] = f2bf(vu); vB[u] = f2bf(vv); spB2[u] = f2bf(vs);
        }
        if (t < 16) {
            float b0 = sw[1296 + t], c0 = 0.f;
            for (int i = 0; i < 16; i++) {
                b0 += sw[1280 + i] * sw[i * 16 + t];
                c0 += sw[(16 + i) * 16 + t];
            }
            biasf[t] = b0; biasf[16 + t] = c0;
        }
    } else if (blockIdx.x == 2) {
        // swt offsets preserved: fcw@0 w1@768 w2@1536
        __shared__ float swt[2816];
        for (int u = t; u < 768;  u += 256) swt[u]        = fcw[u];
        for (int u = t; u < 768;  u += 256) swt[768 + u]  = w1[u];
        for (int u = t; u < 1280; u += 256) swt[1536 + u] = w2[u];
        __syncthreads();
        for (int u = t; u < 2048; u += 256) {
            int kk2 = u >> 9, l = (u >> 3) & 63, j = u & 7, q = l >> 4, o = l & 15;
            int kkp = kk2 * 2 + (q >> 1), i = (q & 1) * 8 + j;
            float v = 0.f;
            for (int o0 = 0; o0 < 16; o0++) {
                float w = (kkp < 3) ? swt[768 + (o0 * 16 + i) * 3 + kkp]
                                    : swt[1536 + (o0 * 16 + i) * 5 + (kkp - 3)];
                v += w * swt[(32 + o0) * 16 + o];
            }
            convA2[u] = f2bf(v);
        }
    } else {
        __shared__ float wtile[32][145];
        int kk = blockIdx.x - 3;
        for (int u = t; u < 32 * 144; u += 256) {
            int r = u / 144, s = u - r * 144;
            int k = kk * 32 + r;
            wtile[r][s] = (k < 144) ? fWl[k * 144 + s] : fWr[(k - 144) * 144 + s];
        }
        __syncthreads();
        for (int u = t; u < 4608; u += 256) {
            int n0 = u >> 9, rem = u & 511;
            int l = rem >> 3, j = rem & 7;
            featB[(kk * 9 + n0) * 512 + rem] =
                f2bf(wtile[(l >> 4) * 8 + j][n0 * 16 + (l & 15)]);
        }
    }
}

// R16: NC=2 capsule-pair blocks. R15 post-mortem: occupancy pinned ~33%
// regardless of LDS cap -> residency isn't binding; waves stall on L2 round
// trips. Biggest per-block L2 consumer = featB (83 KB re-read per block,
// 356 MB chip-wide). 512-thread blocks: waves 0-3 = capsule A, 4-7 = capsule
// B for stage/gather/A/spatial; Stage B pairs: wave w loads tile w's bfrag
// ONCE and runs both capsules' chains from registers (tile 8: w0=capA,
// w1=capB). featB traffic and load-instr ~halved. LDS 34880 B.
__global__ __launch_bounds__(512, 4) void fused_kernel(
    const float* __restrict__ src,
    const float* __restrict__ fbl,
    const int* __restrict__ ws,
    float* __restrict__ out)
{
    const int* g_rp  = ws;
    const int* g_col = ws + 135;
    const float* g_inv = (const float*)(ws + 1207);
    const char* wsb = (const char*)ws;
    const unsigned short* uB     = (const unsigned short*)(wsb + 5376);
    const unsigned short* vB     = (const unsigned short*)(wsb + 6400);
    const unsigned short* spB2   = (const unsigned short*)(wsb + 7424);
    const float*          biasf  = (const float*)(wsb + 8448);
    const unsigned short* convA2 = (const unsigned short*)(wsb + 8704);
    const unsigned short* featB  = (const unsigned short*)(wsb + 12800);

    // 34880 B: xsA@0(7104) xsB@7104(7104) uvA@14208(9984) uvB@24192(9984)
    // s_fbl@34176(576) s_bias@34752(64) s_cs@34816(64).
    // accFA[144][20] f32 @0(11520), accFB @11520(11520) — alias xs/uv regions,
    // used only after those are dead (post-Stage-B barrier).
    __shared__ __align__(16) char smem[34880];
    unsigned short* xsA = (unsigned short*)smem;
    unsigned short* xsB = (unsigned short*)(smem + 7104);
    unsigned short* uvA = (unsigned short*)(smem + 14208);
    unsigned short* uvB = (unsigned short*)(smem + 24192);
    float* accFA  = (float*)smem;
    float* accFB  = (float*)(smem + 11520);
    float* s_fbl  = (float*)(smem + 34176);
    float* s_bias = (float*)(smem + 34752);
    float* s_cs   = (float*)(smem + 34816);

    int t = threadIdx.x;              // 0..511
    int half = t >> 8;                // 0 = capsule A, 1 = capsule B
    int th = t & 255;                 // thread-in-half
    int wave = t >> 6;                // 0..7
    int w4 = wave & 3;                // wave-in-half
    int lane = t & 63;
    int q = lane >> 4, ln = lane & 15;

    unsigned short* xs = half ? xsB : xsA;
    unsigned short* uv = half ? uvB : uvA;

    int ust_w = (w4 == 0) ? 0 : (2 * w4 + 1);   // Stage-A tiles 3/2/2/2 per half

    // capsule mapping: XCD batch-major; pair (c, c+67) per block
    int xcd  = blockIdx.x & 7;
    int slot = blockIdx.x >> 3;        // 0..267
    int bl_  = slot / 67;              // 0..3
    int c0   = slot - bl_ * 67;        // 0..66
    int b    = xcd * 4 + bl_;
    int c    = c0 + half * 67;
    int bc   = b * CAPn + c;
    const float* srcb = src + (size_t)b * (CAPn * SEQn * INVn);
    const float* srcc = srcb + (size_t)c * (SEQn * INVn);

    // own-slice staging; x0..x2 stay LIVE to the epilogue
    const f32x4* s4 = (const f32x4*)srcc;
    f32x4 x0 = s4[th], x1 = s4[th + 256];
    f32x4 x2 = {0.f,0.f,0.f,0.f};
    if (th < 64) x2 = s4[th + 512];

    // ---- Stage 1: float4 gather (per half), 4-edge unrolled ----
    int rs = g_rp[c], re = g_rp[c + 1];
    float idg = g_inv[c];
    f32x4 m0a = {0.f,0.f,0.f,0.f}, m1a = {0.f,0.f,0.f,0.f}, m2a = {0.f,0.f,0.f,0.f};
    f32x4 m0b = {0.f,0.f,0.f,0.f}, m1b = {0.f,0.f,0.f,0.f}, m2b = {0.f,0.f,0.f,0.f};
    int e = rs;
    for (; e + 3 < re; e += 4) {
        int n0_ = g_col[e], n1_ = g_col[e + 1], n2_ = g_col[e + 2], n3_ = g_col[e + 3];
        const f32x4* p0 = (const f32x4*)(srcb + (size_t)n0_ * (SEQn * INVn));
        const f32x4* p1 = (const f32x4*)(srcb + (size_t)n1_ * (SEQn * INVn));
        const f32x4* p2 = (const f32x4*)(srcb + (size_t)n2_ * (SEQn * INVn));
        const f32x4* p3 = (const f32x4*)(srcb + (size_t)n3_ * (SEQn * INVn));
        f32x4 a0 = p0[th],       a1 = p1[th],       a2 = p2[th],       a3 = p3[th];
        f32x4 b0 = p0[th + 256], b1 = p1[th + 256], b2 = p2[th + 256], b3 = p3[th + 256];
        f32x4 c0_ = {0.f,0.f,0.f,0.f}, c1_ = c0_, c2_ = c0_, c3_ = c0_;
        if (th < 64) { c0_ = p0[th + 512]; c1_ = p1[th + 512]; c2_ = p2[th + 512]; c3_ = p3[th + 512]; }
        m0a += a0; m0b += a1; m1a += b0; m1b += b1;
        m0a += a2; m0b += a3; m1a += b2; m1b += b3;
        if (th < 64) { m2a += c0_; m2b += c1_; m2a += c2_; m2b += c3_; }
    }
    for (; e + 1 < re; e += 2) {
        int na = g_col[e], nb = g_col[e + 1];
        const f32x4* pa = (const f32x4*)(srcb + (size_t)na * (SEQn * INVn));
        const f32x4* pb = (const f32x4*)(srcb + (size_t)nb * (SEQn * INVn));
        m0a += pa[th];       m0b += pb[th];
        m1a += pa[th + 256]; m1b += pb[th + 256];
        if (th < 64) { m2a += pa[th + 512]; m2b += pb[th + 512]; }
    }
    if (e < re) {
        int na = g_col[e];
        const f32x4* pa = (const f32x4*)(srcb + (size_t)na * (SEQn * INVn));
        m0a += pa[th]; m1a += pa[th + 256];
        if (th < 64) m2a += pa[th + 512];
    }

    // hoisted tile-invariant fragments (L2-hot) — issued AFTER the gather
    bf16x8 caf0 = *(const bf16x8*)(convA2 + (0 * 64 + lane) * 8);
    bf16x8 caf1 = *(const bf16x8*)(convA2 + (1 * 64 + lane) * 8);
    bf16x8 caf2 = *(const bf16x8*)(convA2 + (2 * 64 + lane) * 8);
    bf16x8 caf3 = *(const bf16x8*)(convA2 + (3 * 64 + lane) * 8);
    bf16x8 sbf = *(const bf16x8*)(spB2 + lane * 8);
    bf16x8 ubf = *(const bf16x8*)(uB + lane * 8);
    bf16x8 vbf = *(const bf16x8*)(vB + lane * 8);

    // means stay in regs, packed: thread th holds mean[s=th>>2(+64/+128)][(th&3)*4..+3]
    f32x4 m0 = (m0a + m0b) * idg, m1 = (m1a + m1b) * idg, m2 = (m2a + m2b) * idg;
    unsigned pA0 = pk2(m0[0], m0[1]), pB0 = pk2(m0[2], m0[3]);
    unsigned pA1 = pk2(m1[0], m1[1]), pB1 = pk2(m1[2], m1[3]);
    unsigned pA2 = pk2(m2[0], m2[1]), pB2 = pk2(m2[2], m2[3]);

    int s0g = th >> 2, i0g = (th & 3) * 4;
    *(short4v*)&xs[(s0g + 2) * 24 + i0g]        = pack4(x0);
    *(short4v*)&xs[(64 + s0g + 2) * 24 + i0g]   = pack4(x1);
    if (th < 64) *(short4v*)&xs[(128 + s0g + 2) * 24 + i0g] = pack4(x2);
    if (th < 64) {                                     // conv halo zeros
        int r = th >> 4, i = th & 15;
        int row = (r < 2) ? r : 144 + r;               // 0,1,146,147
        xs[row * 24 + i] = 0;
    }
    if (t < SEQn) s_fbl[t] = fbl[t];
    if (t < 16) { s_bias[t] = biasf[t]; s_cs[t] = biasf[16 + t]; }
    __syncthreads();

    // ---- Stage A (per half): U=x@H1, V=x@F1 -> uv ----
    #pragma unroll
    for (int tt = 0; tt < 3; tt++) {
        if ((w4 == 0) || (tt < 2)) {
            int mtt = ust_w + tt;
            int sl = mtt * 16 + ln;
            bf16x8 a = {0,0,0,0,0,0,0,0};
            if (q < 2) a = *(const bf16x8*)&xs[(sl + 2) * 24 + q * 8];
            f32x4 au = {0.f,0.f,0.f,0.f}, av = {0.f,0.f,0.f,0.f};
            au = MFMA(a, ubf, au);
            av = MFMA(a, vbf, av);
            *(short4v*)&uv[ln * 312 + mtt * 16 + q * 4]       = pack4(au);
            *(short4v*)&uv[ln * 312 + 144 + mtt * 16 + q * 4] = pack4(av);
        }
    }

    // ---- spatial GEMM (per half): intra-wave bpermute A-frags ----
#define SP_TILE(T, PA, PB, ACC) { \
    int base4 = (ln * 4 + 2 * q) * 4; \
    int d0 = __builtin_amdgcn_ds_bpermute(base4,     (int)(PA)); \
    int d1 = __builtin_amdgcn_ds_bpermute(base4,     (int)(PB)); \
    int d2 = __builtin_amdgcn_ds_bpermute(base4 + 4, (int)(PA)); \
    int d3 = __builtin_amdgcn_ds_bpermute(base4 + 4, (int)(PB)); \
    bf16x8 a_; \
    if (q < 2) { \
        union { int i_[4]; bf16x8 v_; } u_; \
        u_.i_[0] = d0; u_.i_[1] = d1; u_.i_[2] = d2; u_.i_[3] = d3; \
        a_ = u_.v_; \
    } else { \
        a_ = *(const bf16x8*)&xs[((T) * 16 + ln + 2) * 24 + (q & 1) * 8]; \
    } \
    ACC = MFMA(a_, sbf, ACC); }

    f32x4 accS0 = {0.f,0.f,0.f,0.f}, accS1 = accS0, accS2 = accS0;
    SP_TILE(w4,     pA0, pB0, accS0)
    SP_TILE(w4 + 4, pA1, pB1, accS1)
    if (w4 == 0) SP_TILE(8, pA2, pB2, accS2)
#undef SP_TILE
    __syncthreads();   // uvA+uvB published; xsA/xsB stay live for B

    // ---- Stage B: wave w owns tile w for BOTH capsules (bfrag reused) ----
#define B_CHAIN(XS, UV, N0, BF, ACC) { \
    int sl_t = (N0) * 16 + ln; \
    bf16x8 cb[4]; \
    _Pragma("unroll") \
    for (int kk = 0; kk < 4; kk++) { \
        int kkp = kk * 2 + (q >> 1); \
        int off = (kkp < 3) ? (kkp - 1) : (kkp - 5); \
        cb[kk] = *(const bf16x8*)&XS[(sl_t + 2 + off) * 24 + (q & 1) * 8]; } \
    f32x4 acc_ = {0.f,0.f,0.f,0.f}; \
    acc_ = MFMA(caf0, cb[0], acc_); \
    acc_ = MFMA(caf1, cb[1], acc_); \
    acc_ = MFMA(caf2, cb[2], acc_); \
    acc_ = MFMA(caf3, cb[3], acc_); \
    _Pragma("unroll") \
    for (int kk = 0; kk < 9; kk++) { \
        bf16x8 a_ = *(const bf16x8*)&UV[ln * 312 + kk * 32 + q * 8]; \
        acc_ = MFMA(a_, BF[kk], acc_); } \
    ACC = acc_; }

    int myTile = wave;                 // 0..7
    f32x4 accPA = {0.f,0.f,0.f,0.f}, accPB = accPA, accE = accPA;
    {
        bf16x8 bfrag[9];
        #pragma unroll
        for (int kk = 0; kk < 9; kk++)
            bfrag[kk] = *(const bf16x8*)(featB + ((kk * 9 + myTile) * 64 + lane) * 8);
        B_CHAIN(xsA, uvA, myTile, bfrag, accPA)
        B_CHAIN(xsB, uvB, myTile, bfrag, accPB)
    }
    if (wave < 2) {                    // tile 8: wave0=capA, wave1=capB
        bf16x8 bfrag8[9];
        #pragma unroll
        for (int kk = 0; kk < 9; kk++)
            bfrag8[kk] = *(const bf16x8*)(featB + ((kk * 9 + 8) * 64 + lane) * 8);
        if (wave == 0) { B_CHAIN(xsA, uvA, 8, bfrag8, accE) }
        else           { B_CHAIN(xsB, uvB, 8, bfrag8, accE) }
    }
#undef B_CHAIN
    __syncthreads();   // xs/uv dead -> accFA/accFB may alias

    // ---- Scatter B (=): C row = i' = q*4+r, col = s-in-tile = ln ----
    *(f32x4*)&accFA[(myTile * 16 + ln) * 20 + q * 4] = accPA;
    *(f32x4*)&accFB[(myTile * 16 + ln) * 20 + q * 4] = accPB;
    if (wave == 0) *(f32x4*)&accFA[(128 + ln) * 20 + q * 4] = accE;
    if (wave == 1) *(f32x4*)&accFB[(128 + ln) * 20 + q * 4] = accE;
    __syncthreads();

    // ---- Scatter spatial (+=) per half: C row = s = q*4+r, col = i' = ln ----
    float* accF = half ? accFB : accFA;
    #pragma unroll
    for (int r = 0; r < 4; r++)
        accF[(w4 * 16 + q * 4 + r) * 20 + ln] += accS0[r];
    #pragma unroll
    for (int r = 0; r < 4; r++)
        accF[((w4 + 4) * 16 + q * 4 + r) * 20 + ln] += accS1[r];
    if (w4 == 0) {
        #pragma unroll
        for (int r = 0; r < 4; r++)
            accF[(128 + q * 4 + r) * 20 + ln] += accS2[r];
    }
    __syncthreads();

    // ---- Epilogue (per half): chunk-linear stores, residual from regs ----
    f32x4* out4 = (f32x4*)(out + (size_t)bc * (SEQn * INVn));
    int i0 = (th & 3) * 4;
    f32x4 bias4 = *(const f32x4*)&s_bias[i0];
    f32x4 cs4   = *(const f32x4*)&s_cs[i0];
    {
        f32x4 a = *(const f32x4*)&accF[(th >> 2) * 20 + i0];
        out4[th] = a + x0 + bias4 + s_fbl[th >> 2] * cs4;
    }
    {
        int t1 = th + 256;
        f32x4 a = *(const f32x4*)&accF[(t1 >> 2) * 20 + i0];
        out4[t1] = a + x1 + bias4 + s_fbl[t1 >> 2] * cs4;
    }
    if (th < 64) {
        int t2 = th + 512;
        f32x4 a = *(const f32x4*)&accF[(t2 >> 2) * 20 + i0];
        out4[t2] = a + x2 + bias4 + s_fbl[t2 >> 2] * cs4;
    }
}

extern "C" void kernel_launch(void* const* d_in, const int* in_sizes, int n_in,
                              void* d_out, int out_size, void* d_ws, size_t ws_size,
                              hipStream_t stream)
{
    const float* src = (const float*)d_in[0];
    const int* ge = (const int*)d_in[1];
    const int* fe = (const int*)d_in[2];
    const float* Wl  = (const float*)d_in[3];
    const float* blp = (const float*)d_in[4];
    const float* Wr  = (const float*)d_in[5];
    const float* fWl = (const float*)d_in[6];
    const float* fbl = (const float*)d_in[7];
    const float* fWr = (const float*)d_in[8];
    const float* w1  = (const float*)d_in[9];
    const float* w2  = (const float*)d_in[10];
    const float* fcw = (const float*)d_in[11];
    const float* fcb = (const float*)d_in[12];
    float* out = (float*)d_out;
    int* ws = (int*)d_ws;

    hipLaunchKernelGGL(prep_kernel, dim3(12), dim3(256), 0, stream,
                       ge, fe, Wl, Wr, fWl, fWr, w1, w2, fcw, blp, fcb, ws);
    hipLaunchKernelGGL(fused_kernel, dim3(8 * 4 * 67), dim3(512), 0, stream,
                       src, fbl, ws, out);
}

// Round 13
// 150.159 us; speedup vs baseline: 1.3940x; 1.3940x over previous
//
#include <hip/hip_runtime.h>
#include <hip/hip_bf16.h>

#define BZn 32
#define CAPn 134
#define SEQn 144
#define INVn 16
#define ESP 1072
#define EFT 64

// ws layout (bytes):
// 0     : g_rp   135 ints
// 540   : g_col  1072 ints
// 4828  : g_inv  134 floats
// 5376  : uB     512 bf16 (1024 B)  — H1 = AdjW@F1 fragments, K=32 pad
// 6400  : vB     512 bf16           — F1 fragments, K=32 pad
// 7424  : spB2   512 bf16           — [Wl@F0 ; Wr@F0] fragments (K=32)
// 8448  : biasf  32 floats          — bias_i[16] (bl@F0+fcb), cs[16] (colsum F1)
// 8704  : convA2 2048 bf16 (4096 B) — conv weights ⊗ F2, A-fragments
// 12800 : featB  41472 bf16 (82944) — [fWl;fWr] B-fragments (K=288)
// end 95744

typedef __attribute__((ext_vector_type(8))) short bf16x8;
typedef __attribute__((ext_vector_type(4))) short short4v;
typedef __attribute__((ext_vector_type(4))) float f32x4;

#define MFMA(a, b, c) __builtin_amdgcn_mfma_f32_16x16x32_bf16(a, b, c, 0, 0, 0)

__device__ __forceinline__ unsigned short f2bf(float f) {
    union { float f; unsigned u; } v; v.f = f;
    unsigned r = v.u + 0x7fff + ((v.u >> 16) & 1);
    return (unsigned short)(r >> 16);
}
__device__ __forceinline__ unsigned pk2(float a, float b) {
    float2 v; v.x = a; v.y = b;
    union { __hip_bfloat162 h; unsigned u; } c;
    c.h = __float22bfloat162_rn(v);
    return c.u;
}
__device__ __forceinline__ short4v pack4(f32x4 v) {
    union { unsigned u[2]; short4v s; } r;
    r.u[0] = pk2(v[0], v[1]);
    r.u[1] = pk2(v[2], v[3]);
    return r.s;
}

// R17 prep: finer job-parallelism. R13's critical path was the featB slab
// block (LDS-staged 32x144 + 4608 writes, 9 CUs). featB elements are pure
// per-element functions of fWl/fWr -> split by (kk,n0): 81 tiny blocks,
// direct read->convert->write, no LDS, no barrier. grid = 3 + 81 = 84.
__global__ __launch_bounds__(256) void prep_kernel(
    const int* __restrict__ ge, const int* __restrict__ fe,
    const float* __restrict__ Wl,  const float* __restrict__ Wr,
    const float* __restrict__ fWl, const float* __restrict__ fWr,
    const float* __restrict__ w1,  const float* __restrict__ w2,
    const float* __restrict__ fcw, const float* __restrict__ bl,
    const float* __restrict__ fcb,
    int* __restrict__ ws)
{
    int t = threadIdx.x;
    char* wsb = (char*)ws;
    unsigned short* uB     = (unsigned short*)(wsb + 5376);
    unsigned short* vB     = (unsigned short*)(wsb + 6400);
    unsigned short* spB2   = (unsigned short*)(wsb + 7424);
    float*          biasf  = (float*)(wsb + 8448);
    unsigned short* convA2 = (unsigned short*)(wsb + 8704);
    unsigned short* featB  = (unsigned short*)(wsb + 12800);

    if (blockIdx.x == 0) {
        int* g_rp  = ws;
        int* g_col = ws + 135;
        float* g_inv = (float*)(ws + 1207);
        __shared__ int cnt[CAPn], off[CAPn];
        for (int c0 = t; c0 < CAPn; c0 += 256) cnt[c0] = 0;
        __syncthreads();
        for (int e = t; e < ESP; e += 256) atomicAdd(&cnt[ge[ESP + e]], 1);
        __syncthreads();
        if (t == 0) {
            int run = 0;
            for (int c0 = 0; c0 < CAPn; c0++) {
                off[c0] = run; g_rp[c0] = run;
                g_inv[c0] = 1.0f / fmaxf((float)cnt[c0], 1.0f);
                run += cnt[c0];
            }
            g_rp[CAPn] = run;
        }
        __syncthreads();
        for (int c0 = t; c0 < CAPn; c0 += 256) cnt[c0] = 0;
        __syncthreads();
        for (int e = t; e < ESP; e += 256) {
            int d = ge[ESP + e];
            int p = off[d] + atomicAdd(&cnt[d], 1);
            g_col[p] = ge[e];
        }
    } else if (blockIdx.x == 1) {
        // sw: fcw@0(768) Wl@768(256) Wr@1024(256) bl@1280(16) fcb@1296(16)
        __shared__ float sw[1312];
        __shared__ int fm[256];
        __shared__ float finv[16];
        for (int u = t; u < 768; u += 256) sw[u] = fcw[u];
        if (t < 256) sw[768 + t]  = Wl[t];
        if (t < 256) sw[1024 + t] = Wr[t];
        if (t < 16)  sw[1280 + t] = bl[t];
        if (t < 16)  sw[1296 + t] = fcb[t];
        fm[t] = 0;
        __syncthreads();
        if (t < EFT) atomicAdd(&fm[fe[t] * 16 + fe[EFT + t]], 1);
        __syncthreads();
        if (t < 16) {
            int dg = 0;
            for (int j = 0; j < 16; j++) dg += fm[j * 16 + t];
            finv[t] = 1.0f / fmaxf((float)dg, 1.0f);
        }
        __syncthreads();
        for (int u = t; u < 512; u += 256) {
            int l = u >> 3, j = u & 7, k = (l >> 4) * 8 + j, ip = l & 15;
            float vu = 0.f, vv = 0.f, vs = 0.f;
            if (k < 16) {
                for (int i = 0; i < 16; i++)
                    vu += (float)fm[k * 16 + i] * finv[i] * sw[(16 + i) * 16 + ip];
                vv = sw[(16 + k) * 16 + ip];
                for (int i = 0; i < 16; i++) vs += sw[768 + k * 16 + i] * sw[i * 16 + ip];
            } else {
                for (int i = 0; i < 16; i++) vs += sw[1024 + (k - 16) * 16 + i] * sw[i * 16 + ip];
            }
            uB[u] = f2bf(vu); vB[u] = f2bf(vv); spB2[u] = f2bf(vs);
        }
        if (t < 16) {
            float b0 = sw[1296 + t], c0 = 0.f;
            for (int i = 0; i < 16; i++) {
                b0 += sw[1280 + i] * sw[i * 16 + t];
                c0 += sw[(16 + i) * 16 + t];
            }
            biasf[t] = b0; biasf[16 + t] = c0;
        }
    } else if (blockIdx.x == 2) {
        // swt offsets preserved: fcw@0 w1@768 w2@1536
        __shared__ float swt[2816];
        for (int u = t; u < 768;  u += 256) swt[u]        = fcw[u];
        for (int u = t; u < 768;  u += 256) swt[768 + u]  = w1[u];
        for (int u = t; u < 1280; u += 256) swt[1536 + u] = w2[u];
        __syncthreads();
        for (int u = t; u < 2048; u += 256) {
            int kk2 = u >> 9, l = (u >> 3) & 63, j = u & 7, q = l >> 4, o = l & 15;
            int kkp = kk2 * 2 + (q >> 1), i = (q & 1) * 8 + j;
            float v = 0.f;
            for (int o0 = 0; o0 < 16; o0++) {
                float w = (kkp < 3) ? swt[768 + (o0 * 16 + i) * 3 + kkp]
                                    : swt[1536 + (o0 * 16 + i) * 5 + (kkp - 3)];
                v += w * swt[(32 + o0) * 16 + o];
            }
            convA2[u] = f2bf(v);
        }
    } else {
        // featB micro-tile (kk, n0): 512 elements, direct convert, no LDS.
        // featB[(kk*9+n0)*512+u] = f2bf(w[(kk*32 + (l>>4)*8 + j)][n0*16 + (l&15)])
        int idx = blockIdx.x - 3;          // 0..80
        int kk = idx / 9, n0 = idx - (idx / 9) * 9;
        for (int u = t; u < 512; u += 256) {
            int l = u >> 3, j = u & 7;
            int k = kk * 32 + (l >> 4) * 8 + j;
            int col = n0 * 16 + (l & 15);
            float v = (k < 144) ? fWl[k * 144 + col] : fWr[(k - 144) * 144 + col];
            featB[(kk * 9 + n0) * 512 + u] = f2bf(v);
        }
    }
}

// R17 fused: R14 verbatim (best clean: 47.3 µs, FETCH 19.74/WRITE 38.59,
// VGPR 64, LDS 25088). R15 (LDS diet) null; R16 (NC=2 featB-share) spilled
// (FETCH 99/WRITE 227) — reverted.
__global__ __launch_bounds__(256, 4) void fused_kernel(
    const float* __restrict__ src,
    const float* __restrict__ fbl,
    const int* __restrict__ ws,
    float* __restrict__ out)
{
    const int* g_rp  = ws;
    const int* g_col = ws + 135;
    const float* g_inv = (const float*)(ws + 1207);
    const char* wsb = (const char*)ws;
    const unsigned short* uB     = (const unsigned short*)(wsb + 5376);
    const unsigned short* vB     = (const unsigned short*)(wsb + 6400);
    const unsigned short* spB2   = (const unsigned short*)(wsb + 7424);
    const float*          biasf  = (const float*)(wsb + 8448);
    const unsigned short* convA2 = (const unsigned short*)(wsb + 8704);
    const unsigned short* featB  = (const unsigned short*)(wsb + 12800);

    // 24704 B -> 6 blocks/CU. xs[148][24]@0, mt[144][24]@7104, uv[16][312]@14016,
    // sfbl@24000, sbias@24576, scs@24640. accF[144][16] f32 (9216 B) aliases
    // smem[0..9216) = xs + mt head — only used after xs/mt are dead.
    __shared__ __align__(16) char smem[24704];
    unsigned short* xs = (unsigned short*)smem;
    unsigned short* mt = (unsigned short*)(smem + 7104);
    unsigned short* uv = (unsigned short*)(smem + 14016);
    float* accF   = (float*)smem;
    float* s_fbl  = (float*)(smem + 24000);
    float* s_bias = (float*)(smem + 24576);
    float* s_cs   = (float*)(smem + 24640);

    int t = threadIdx.x;
    int wave = t >> 6, lane = t & 63;
    int q = lane >> 4, ln = lane & 15;

    int ust_w = (wave == 0) ? 0 : (2 * wave + 1);   // tiles 3/2/2/2
    int sst_w = 2 * wave;                           // tiles 2/2/2/3

    int xcd  = blockIdx.x & 7;
    int slot = blockIdx.x >> 3;
    int bl_  = slot / 134;
    int c    = slot - bl_ * 134;
    int b    = xcd * 4 + bl_;
    int bc   = b * CAPn + c;
    const float* srcb = src + (size_t)b * (CAPn * SEQn * INVn);
    const float* srcc = srcb + (size_t)c * (SEQn * INVn);

    // own-slice staging; x0..x2 stay LIVE to the epilogue (residual in regs)
    const f32x4* s4 = (const f32x4*)srcc;
    f32x4 x0 = s4[t], x1 = s4[t + 256];
    f32x4 x2 = {0.f,0.f,0.f,0.f};
    if (t < 64) x2 = s4[t + 512];

    // ---- Stage 1: float4 gather, 4-edge unrolled ----
    int rs = g_rp[c], re = g_rp[c + 1];
    float idg = g_inv[c];
    f32x4 m0a = {0.f,0.f,0.f,0.f}, m1a = {0.f,0.f,0.f,0.f}, m2a = {0.f,0.f,0.f,0.f};
    f32x4 m0b = {0.f,0.f,0.f,0.f}, m1b = {0.f,0.f,0.f,0.f}, m2b = {0.f,0.f,0.f,0.f};
    int e = rs;
    for (; e + 3 < re; e += 4) {
        int n0_ = g_col[e], n1_ = g_col[e + 1], n2_ = g_col[e + 2], n3_ = g_col[e + 3];
        const f32x4* p0 = (const f32x4*)(srcb + (size_t)n0_ * (SEQn * INVn));
        const f32x4* p1 = (const f32x4*)(srcb + (size_t)n1_ * (SEQn * INVn));
        const f32x4* p2 = (const f32x4*)(srcb + (size_t)n2_ * (SEQn * INVn));
        const f32x4* p3 = (const f32x4*)(srcb + (size_t)n3_ * (SEQn * INVn));
        f32x4 a0 = p0[t],       a1 = p1[t],       a2 = p2[t],       a3 = p3[t];
        f32x4 b0 = p0[t + 256], b1 = p1[t + 256], b2 = p2[t + 256], b3 = p3[t + 256];
        f32x4 c0 = {0.f,0.f,0.f,0.f}, c1 = c0, c2 = c0, c3 = c0;
        if (t < 64) { c0 = p0[t + 512]; c1 = p1[t + 512]; c2 = p2[t + 512]; c3 = p3[t + 512]; }
        m0a += a0; m0b += a1; m1a += b0; m1b += b1;
        m0a += a2; m0b += a3; m1a += b2; m1b += b3;
        if (t < 64) { m2a += c0; m2b += c1; m2a += c2; m2b += c3; }
    }
    for (; e + 1 < re; e += 2) {
        int na = g_col[e], nb = g_col[e + 1];
        const f32x4* pa = (const f32x4*)(srcb + (size_t)na * (SEQn * INVn));
        const f32x4* pb = (const f32x4*)(srcb + (size_t)nb * (SEQn * INVn));
        m0a += pa[t];       m0b += pb[t];
        m1a += pa[t + 256]; m1b += pb[t + 256];
        if (t < 64) { m2a += pa[t + 512]; m2b += pb[t + 512]; }
    }
    if (e < re) {
        int na = g_col[e];
        const f32x4* pa = (const f32x4*)(srcb + (size_t)na * (SEQn * INVn));
        m0a += pa[t]; m1a += pa[t + 256];
        if (t < 64) m2a += pa[t + 512];
    }

    // hoisted tile-invariant fragments (L2-hot) — issued AFTER the gather
    bf16x8 caf0 = *(const bf16x8*)(convA2 + (0 * 64 + lane) * 8);
    bf16x8 caf1 = *(const bf16x8*)(convA2 + (1 * 64 + lane) * 8);
    bf16x8 caf2 = *(const bf16x8*)(convA2 + (2 * 64 + lane) * 8);
    bf16x8 caf3 = *(const bf16x8*)(convA2 + (3 * 64 + lane) * 8);
    bf16x8 sbf = *(const bf16x8*)(spB2 + lane * 8);
    bf16x8 ubf = *(const bf16x8*)(uB + lane * 8);
    bf16x8 vbf = *(const bf16x8*)(vB + lane * 8);

    int s0g = t >> 2, i0g = (t & 3) * 4;
    f32x4 m0 = (m0a + m0b) * idg, m1 = (m1a + m1b) * idg, m2 = (m2a + m2b) * idg;
    *(short4v*)&mt[s0g * 24 + i0g]         = pack4(m0);
    *(short4v*)&mt[(64 + s0g) * 24 + i0g]  = pack4(m1);
    if (t < 64) *(short4v*)&mt[(128 + s0g) * 24 + i0g] = pack4(m2);

    *(short4v*)&xs[(s0g + 2) * 24 + i0g]        = pack4(x0);
    *(short4v*)&xs[(64 + s0g + 2) * 24 + i0g]   = pack4(x1);
    if (t < 64) *(short4v*)&xs[(128 + s0g + 2) * 24 + i0g] = pack4(x2);
    if (t < 64) {                                      // conv halo zeros
        int r = t >> 4, i = t & 15;
        int row = (r < 2) ? r : 144 + r;               // 0,1,146,147
        xs[row * 24 + i] = 0;
    }
    if (t < SEQn) s_fbl[t] = fbl[t];
    if (t < 16) { s_bias[t] = biasf[t]; s_cs[t] = biasf[16 + t]; }
    __syncthreads();

    // ---- Stage A: U=x@H1, V=x@F1 -> uv; spatial GEMM -> accS regs ----
    #pragma unroll
    for (int tt = 0; tt < 3; tt++) {
        if ((wave == 0) || (tt < 2)) {
            int mtt = ust_w + tt;
            int sl = mtt * 16 + ln;
            bf16x8 a = {0,0,0,0,0,0,0,0};
            if (q < 2) a = *(const bf16x8*)&xs[(sl + 2) * 24 + q * 8];
            f32x4 au = {0.f,0.f,0.f,0.f}, av = {0.f,0.f,0.f,0.f};
            au = MFMA(a, ubf, au);
            av = MFMA(a, vbf, av);
            *(short4v*)&uv[ln * 312 + mtt * 16 + q * 4]       = pack4(au);
            *(short4v*)&uv[ln * 312 + 144 + mtt * 16 + q * 4] = pack4(av);
        }
    }
    f32x4 accS0 = {0.f,0.f,0.f,0.f}, accS1 = accS0, accS2 = accS0;
    {
        int sl = (sst_w + 0) * 16 + ln;
        const unsigned short* ap = (q < 2) ? &mt[sl * 24 + (q & 1) * 8]
                                           : &xs[(sl + 2) * 24 + (q & 1) * 8];
        accS0 = MFMA(*(const bf16x8*)ap, sbf, accS0);
    }
    {
        int sl = (sst_w + 1) * 16 + ln;
        const unsigned short* ap = (q < 2) ? &mt[sl * 24 + (q & 1) * 8]
                                           : &xs[(sl + 2) * 24 + (q & 1) * 8];
        accS1 = MFMA(*(const bf16x8*)ap, sbf, accS1);
    }
    if (wave == 3) {
        int sl = (sst_w + 2) * 16 + ln;
        const unsigned short* ap = (q < 2) ? &mt[sl * 24 + (q & 1) * 8]
                                           : &xs[(sl + 2) * 24 + (q & 1) * 8];
        accS2 = MFMA(*(const bf16x8*)ap, sbf, accS2);
    }
    __syncthreads();   // mt (mean) dead after this barrier

    // ---- Stage B compute: conv (4 MFMA) + feature K=288 (9 MFMA) -> regs ----
#define B_TILE(N0, ACC) { \
    int n0_t = (N0); int sl_t = n0_t * 16 + ln; \
    bf16x8 bfrag[9]; \
    _Pragma("unroll") \
    for (int kk = 0; kk < 9; kk++) \
        bfrag[kk] = *(const bf16x8*)(featB + ((kk * 9 + n0_t) * 64 + lane) * 8); \
    bf16x8 cb[4]; \
    _Pragma("unroll") \
    for (int kk = 0; kk < 4; kk++) { \
        int kkp = kk * 2 + (q >> 1); \
        int off = (kkp < 3) ? (kkp - 1) : (kkp - 5); \
        cb[kk] = *(const bf16x8*)&xs[(sl_t + 2 + off) * 24 + (q & 1) * 8]; } \
    f32x4 acc_ = {0.f,0.f,0.f,0.f}; \
    acc_ = MFMA(caf0, cb[0], acc_); \
    acc_ = MFMA(caf1, cb[1], acc_); \
    acc_ = MFMA(caf2, cb[2], acc_); \
    acc_ = MFMA(caf3, cb[3], acc_); \
    _Pragma("unroll") \
    for (int kk = 0; kk < 9; kk++) { \
        bf16x8 a_ = *(const bf16x8*)&uv[ln * 312 + kk * 32 + q * 8]; \
        acc_ = MFMA(a_, bfrag[kk], acc_); } \
    ACC = acc_; }

    f32x4 accB0 = {0.f,0.f,0.f,0.f}, accB1 = accB0, accB2 = accB0;
    B_TILE(ust_w + 0, accB0)
    B_TILE(ust_w + 1, accB1)
    if (wave == 0) B_TILE(ust_w + 2, accB2)
#undef B_TILE
    __syncthreads();   // xs, uv dead -> accF may now alias smem[0..9216)

    // ---- Scatter B (=): C layout row = i' = q*4+r, col = s-in-tile = ln ----
    *(f32x4*)&accF[(((ust_w + 0) * 16 + ln) * 16) + q * 4] = accB0;
    *(f32x4*)&accF[(((ust_w + 1) * 16 + ln) * 16) + q * 4] = accB1;
    if (wave == 0)
        *(f32x4*)&accF[(((ust_w + 2) * 16 + ln) * 16) + q * 4] = accB2;
    __syncthreads();

    // ---- Scatter spatial (+=): C layout row = s = q*4+r, col = i' = ln ----
    #pragma unroll
    for (int r = 0; r < 4; r++)
        accF[((sst_w + 0) * 16 + q * 4 + r) * 16 + ln] += accS0[r];
    #pragma unroll
    for (int r = 0; r < 4; r++)
        accF[((sst_w + 1) * 16 + q * 4 + r) * 16 + ln] += accS1[r];
    if (wave == 3) {
        #pragma unroll
        for (int r = 0; r < 4; r++)
            accF[((sst_w + 2) * 16 + q * 4 + r) * 16 + ln] += accS2[r];
    }
    __syncthreads();

    // ---- Epilogue: chunk-linear. acc (LDS f32x4) + residual (regs) + bias ----
    f32x4* out4 = (f32x4*)(out + (size_t)bc * (SEQn * INVn));
    int i0 = (t & 3) * 4;
    f32x4 bias4 = *(const f32x4*)&s_bias[i0];
    f32x4 cs4   = *(const f32x4*)&s_cs[i0];
    {
        f32x4 a = *(const f32x4*)&accF[4 * t];
        out4[t] = a + x0 + bias4 + s_fbl[t >> 2] * cs4;
    }
    {
        f32x4 a = *(const f32x4*)&accF[4 * (t + 256)];
        out4[t + 256] = a + x1 + bias4 + s_fbl[(t + 256) >> 2] * cs4;
    }
    if (t < 64) {
        f32x4 a = *(const f32x4*)&accF[4 * (t + 512)];
        out4[t + 512] = a + x2 + bias4 + s_fbl[(t + 512) >> 2] * cs4;
    }
}

extern "C" void kernel_launch(void* const* d_in, const int* in_sizes, int n_in,
                              void* d_out, int out_size, void* d_ws, size_t ws_size,
                              hipStream_t stream)
{
    const float* src = (const float*)d_in[0];
    const int* ge = (const int*)d_in[1];
    const int* fe = (const int*)d_in[2];
    const float* Wl  = (const float*)d_in[3];
    const float* blp = (const float*)d_in[4];
    const float* Wr  = (const float*)d_in[5];
    const float* fWl = (const float*)d_in[6];
    const float* fbl = (const float*)d_in[7];
    const float* fWr = (const float*)d_in[8];
    const float* w1  = (const float*)d_in[9];
    const float* w2  = (const float*)d_in[10];
    const float* fcw = (const float*)d_in[11];
    const float* fcb = (const float*)d_in[12];
    float* out = (float*)d_out;
    int* ws = (int*)d_ws;

    hipLaunchKernelGGL(prep_kernel, dim3(84), dim3(256), 0, stream,
                       ge, fe, Wl, Wr, fWl, fWr, w1, w2, fcw, blp, fcb, ws);
    hipLaunchKernelGGL(fused_kernel, dim3(BZn * CAPn), dim3(256), 0, stream,
                       src, fbl, ws, out);
}

// Round 14
// 147.541 us; speedup vs baseline: 1.4187x; 1.0177x over previous
//
#include <hip/hip_runtime.h>
#include <hip/hip_bf16.h>

#define BZn 32
#define CAPn 134
#define SEQn 144
#define INVn 16
#define ESP 1072
#define EFT 64

// ws layout (bytes):
// 0     : g_rp   135 ints
// 540   : g_col  1072 ints
// 4828  : g_inv  134 floats
// 5376  : uB     512 bf16 (1024 B)  — H1 = AdjW@F1 fragments, K=32 pad
// 6400  : vB     512 bf16           — F1 fragments, K=32 pad
// 7424  : spB2   512 bf16           — [Wl@F0 ; Wr@F0] fragments (K=32)
// 8448  : biasf  32 floats          — bias_i[16] (bl@F0+fcb), cs[16] (colsum F1)
// 8704  : convA2 2048 bf16 (4096 B) — conv weights ⊗ F2, A-fragments
// 12800 : featB  41472 bf16 (82944) — [fWl;fWr] B-fragments (K=288)
// end 95744

typedef __attribute__((ext_vector_type(8))) short bf16x8;
typedef __attribute__((ext_vector_type(4))) short short4v;
typedef __attribute__((ext_vector_type(4))) float f32x4;

#define MFMA(a, b, c) __builtin_amdgcn_mfma_f32_16x16x32_bf16(a, b, c, 0, 0, 0)

__device__ __forceinline__ unsigned short f2bf(float f) {
    union { float f; unsigned u; } v; v.f = f;
    unsigned r = v.u + 0x7fff + ((v.u >> 16) & 1);
    return (unsigned short)(r >> 16);
}
__device__ __forceinline__ unsigned pk2(float a, float b) {
    float2 v; v.x = a; v.y = b;
    union { __hip_bfloat162 h; unsigned u; } c;
    c.h = __float22bfloat162_rn(v);
    return c.u;
}
__device__ __forceinline__ short4v pack4(f32x4 v) {
    union { unsigned u[2]; short4v s; } r;
    r.u[0] = pk2(v[0], v[1]);
    r.u[1] = pk2(v[2], v[3]);
    return r.s;
}

// R17 prep (kept): fine job-parallelism, grid 84. b0=CSR, b1=combos+biasf,
// b2=convA2, b3..b83=featB micro-tiles (direct convert, no LDS).
__global__ __launch_bounds__(256) void prep_kernel(
    const int* __restrict__ ge, const int* __restrict__ fe,
    const float* __restrict__ Wl,  const float* __restrict__ Wr,
    const float* __restrict__ fWl, const float* __restrict__ fWr,
    const float* __restrict__ w1,  const float* __restrict__ w2,
    const float* __restrict__ fcw, const float* __restrict__ bl,
    const float* __restrict__ fcb,
    int* __restrict__ ws)
{
    int t = threadIdx.x;
    char* wsb = (char*)ws;
    unsigned short* uB     = (unsigned short*)(wsb + 5376);
    unsigned short* vB     = (unsigned short*)(wsb + 6400);
    unsigned short* spB2   = (unsigned short*)(wsb + 7424);
    float*          biasf  = (float*)(wsb + 8448);
    unsigned short* convA2 = (unsigned short*)(wsb + 8704);
    unsigned short* featB  = (unsigned short*)(wsb + 12800);

    if (blockIdx.x == 0) {
        int* g_rp  = ws;
        int* g_col = ws + 135;
        float* g_inv = (float*)(ws + 1207);
        __shared__ int cnt[CAPn], off[CAPn];
        for (int c0 = t; c0 < CAPn; c0 += 256) cnt[c0] = 0;
        __syncthreads();
        for (int e = t; e < ESP; e += 256) atomicAdd(&cnt[ge[ESP + e]], 1);
        __syncthreads();
        if (t == 0) {
            int run = 0;
            for (int c0 = 0; c0 < CAPn; c0++) {
                off[c0] = run; g_rp[c0] = run;
                g_inv[c0] = 1.0f / fmaxf((float)cnt[c0], 1.0f);
                run += cnt[c0];
            }
            g_rp[CAPn] = run;
        }
        __syncthreads();
        for (int c0 = t; c0 < CAPn; c0 += 256) cnt[c0] = 0;
        __syncthreads();
        for (int e = t; e < ESP; e += 256) {
            int d = ge[ESP + e];
            int p = off[d] + atomicAdd(&cnt[d], 1);
            g_col[p] = ge[e];
        }
    } else if (blockIdx.x == 1) {
        // sw: fcw@0(768) Wl@768(256) Wr@1024(256) bl@1280(16) fcb@1296(16)
        __shared__ float sw[1312];
        __shared__ int fm[256];
        __shared__ float finv[16];
        for (int u = t; u < 768; u += 256) sw[u] = fcw[u];
        if (t < 256) sw[768 + t]  = Wl[t];
        if (t < 256) sw[1024 + t] = Wr[t];
        if (t < 16)  sw[1280 + t] = bl[t];
        if (t < 16)  sw[1296 + t] = fcb[t];
        fm[t] = 0;
        __syncthreads();
        if (t < EFT) atomicAdd(&fm[fe[t] * 16 + fe[EFT + t]], 1);
        __syncthreads();
        if (t < 16) {
            int dg = 0;
            for (int j = 0; j < 16; j++) dg += fm[j * 16 + t];
            finv[t] = 1.0f / fmaxf((float)dg, 1.0f);
        }
        __syncthreads();
        for (int u = t; u < 512; u += 256) {
            int l = u >> 3, j = u & 7, k = (l >> 4) * 8 + j, ip = l & 15;
            float vu = 0.f, vv = 0.f, vs = 0.f;
            if (k < 16) {
                for (int i = 0; i < 16; i++)
                    vu += (float)fm[k * 16 + i] * finv[i] * sw[(16 + i) * 16 + ip];
                vv = sw[(16 + k) * 16 + ip];
                for (int i = 0; i < 16; i++) vs += sw[768 + k * 16 + i] * sw[i * 16 + ip];
            } else {
                for (int i = 0; i < 16; i++) vs += sw[1024 + (k - 16) * 16 + i] * sw[i * 16 + ip];
            }
            uB[u] = f2bf(vu); vB[u] = f2bf(vv); spB2[u] = f2bf(vs);
        }
        if (t < 16) {
            float b0 = sw[1296 + t], c0 = 0.f;
            for (int i = 0; i < 16; i++) {
                b0 += sw[1280 + i] * sw[i * 16 + t];
                c0 += sw[(16 + i) * 16 + t];
            }
            biasf[t] = b0; biasf[16 + t] = c0;
        }
    } else if (blockIdx.x == 2) {
        // swt offsets preserved: fcw@0 w1@768 w2@1536
        __shared__ float swt[2816];
        for (int u = t; u < 768;  u += 256) swt[u]        = fcw[u];
        for (int u = t; u < 768;  u += 256) swt[768 + u]  = w1[u];
        for (int u = t; u < 1280; u += 256) swt[1536 + u] = w2[u];
        __syncthreads();
        for (int u = t; u < 2048; u += 256) {
            int kk2 = u >> 9, l = (u >> 3) & 63, j = u & 7, q = l >> 4, o = l & 15;
            int kkp = kk2 * 2 + (q >> 1), i = (q & 1) * 8 + j;
            float v = 0.f;
            for (int o0 = 0; o0 < 16; o0++) {
                float w = (kkp < 3) ? swt[768 + (o0 * 16 + i) * 3 + kkp]
                                    : swt[1536 + (o0 * 16 + i) * 5 + (kkp - 3)];
                v += w * swt[(32 + o0) * 16 + o];
            }
            convA2[u] = f2bf(v);
        }
    } else {
        // featB micro-tile (kk, n0): 512 elements, direct convert, no LDS.
        int idx = blockIdx.x - 3;          // 0..80
        int kk = idx / 9, n0 = idx - (idx / 9) * 9;
        for (int u = t; u < 512; u += 256) {
            int l = u >> 3, j = u & 7;
            int k = kk * 32 + (l >> 4) * 8 + j;
            int col = n0 * 16 + (l & 15);
            float v = (k < 144) ? fWl[k * 144 + col] : fWr[(k - 144) * 144 + col];
            featB[(kk * 9 + n0) * 512 + u] = f2bf(v);
        }
    }
}

// R18: R17 fused + (a) T5 setprio(1) around MFMA clusters — cross-BLOCK wave
// phase diversity (6 blocks/CU at gather vs MFMA phases) is the attn-like
// regime where setprio measured +4-7%; (b) scatter-phase merge: spatial acc
// goes to its own aliased buffer accFS (mt/uv corpse), so B-scatter and
// S-scatter are both pure writes in ONE phase -> one barrier removed, and
// the old scalar += LDS reads become 2.25 vector loads in the epilogue.
__global__ __launch_bounds__(256, 4) void fused_kernel(
    const float* __restrict__ src,
    const float* __restrict__ fbl,
    const int* __restrict__ ws,
    float* __restrict__ out)
{
    const int* g_rp  = ws;
    const int* g_col = ws + 135;
    const float* g_inv = (const float*)(ws + 1207);
    const char* wsb = (const char*)ws;
    const unsigned short* uB     = (const unsigned short*)(wsb + 5376);
    const unsigned short* vB     = (const unsigned short*)(wsb + 6400);
    const unsigned short* spB2   = (const unsigned short*)(wsb + 7424);
    const float*          biasf  = (const float*)(wsb + 8448);
    const unsigned short* convA2 = (const unsigned short*)(wsb + 8704);
    const unsigned short* featB  = (const unsigned short*)(wsb + 12800);

    // 24704 B -> 6 blocks/CU. xs[148][24]@0, mt[144][24]@7104, uv[16][312]@14016,
    // sfbl@24000, sbias@24576, scs@24640.
    // accF[144][16] f32 @0 (9216) aliases xs+mt-head; accFS[144][16] @11520
    // (9216, ends 20736) aliases mt-tail+uv — both only used post-Stage-B.
    __shared__ __align__(16) char smem[24704];
    unsigned short* xs = (unsigned short*)smem;
    unsigned short* mt = (unsigned short*)(smem + 7104);
    unsigned short* uv = (unsigned short*)(smem + 14016);
    float* accF   = (float*)smem;
    float* accFS  = (float*)(smem + 11520);
    float* s_fbl  = (float*)(smem + 24000);
    float* s_bias = (float*)(smem + 24576);
    float* s_cs   = (float*)(smem + 24640);

    int t = threadIdx.x;
    int wave = t >> 6, lane = t & 63;
    int q = lane >> 4, ln = lane & 15;

    int ust_w = (wave == 0) ? 0 : (2 * wave + 1);   // tiles 3/2/2/2
    int sst_w = 2 * wave;                           // tiles 2/2/2/3

    int xcd  = blockIdx.x & 7;
    int slot = blockIdx.x >> 3;
    int bl_  = slot / 134;
    int c    = slot - bl_ * 134;
    int b    = xcd * 4 + bl_;
    int bc   = b * CAPn + c;
    const float* srcb = src + (size_t)b * (CAPn * SEQn * INVn);
    const float* srcc = srcb + (size_t)c * (SEQn * INVn);

    // own-slice staging; x0..x2 stay LIVE to the epilogue (residual in regs)
    const f32x4* s4 = (const f32x4*)srcc;
    f32x4 x0 = s4[t], x1 = s4[t + 256];
    f32x4 x2 = {0.f,0.f,0.f,0.f};
    if (t < 64) x2 = s4[t + 512];

    // ---- Stage 1: float4 gather, 4-edge unrolled ----
    int rs = g_rp[c], re = g_rp[c + 1];
    float idg = g_inv[c];
    f32x4 m0a = {0.f,0.f,0.f,0.f}, m1a = {0.f,0.f,0.f,0.f}, m2a = {0.f,0.f,0.f,0.f};
    f32x4 m0b = {0.f,0.f,0.f,0.f}, m1b = {0.f,0.f,0.f,0.f}, m2b = {0.f,0.f,0.f,0.f};
    int e = rs;
    for (; e + 3 < re; e += 4) {
        int n0_ = g_col[e], n1_ = g_col[e + 1], n2_ = g_col[e + 2], n3_ = g_col[e + 3];
        const f32x4* p0 = (const f32x4*)(srcb + (size_t)n0_ * (SEQn * INVn));
        const f32x4* p1 = (const f32x4*)(srcb + (size_t)n1_ * (SEQn * INVn));
        const f32x4* p2 = (const f32x4*)(srcb + (size_t)n2_ * (SEQn * INVn));
        const f32x4* p3 = (const f32x4*)(srcb + (size_t)n3_ * (SEQn * INVn));
        f32x4 a0 = p0[t],       a1 = p1[t],       a2 = p2[t],       a3 = p3[t];
        f32x4 b0 = p0[t + 256], b1 = p1[t + 256], b2 = p2[t + 256], b3 = p3[t + 256];
        f32x4 c0 = {0.f,0.f,0.f,0.f}, c1 = c0, c2 = c0, c3 = c0;
        if (t < 64) { c0 = p0[t + 512]; c1 = p1[t + 512]; c2 = p2[t + 512]; c3 = p3[t + 512]; }
        m0a += a0; m0b += a1; m1a += b0; m1b += b1;
        m0a += a2; m0b += a3; m1a += b2; m1b += b3;
        if (t < 64) { m2a += c0; m2b += c1; m2a += c2; m2b += c3; }
    }
    for (; e + 1 < re; e += 2) {
        int na = g_col[e], nb = g_col[e + 1];
        const f32x4* pa = (const f32x4*)(srcb + (size_t)na * (SEQn * INVn));
        const f32x4* pb = (const f32x4*)(srcb + (size_t)nb * (SEQn * INVn));
        m0a += pa[t];       m0b += pb[t];
        m1a += pa[t + 256]; m1b += pb[t + 256];
        if (t < 64) { m2a += pa[t + 512]; m2b += pb[t + 512]; }
    }
    if (e < re) {
        int na = g_col[e];
        const f32x4* pa = (const f32x4*)(srcb + (size_t)na * (SEQn * INVn));
        m0a += pa[t]; m1a += pa[t + 256];
        if (t < 64) m2a += pa[t + 512];
    }

    // hoisted tile-invariant fragments (L2-hot) — issued AFTER the gather
    bf16x8 caf0 = *(const bf16x8*)(convA2 + (0 * 64 + lane) * 8);
    bf16x8 caf1 = *(const bf16x8*)(convA2 + (1 * 64 + lane) * 8);
    bf16x8 caf2 = *(const bf16x8*)(convA2 + (2 * 64 + lane) * 8);
    bf16x8 caf3 = *(const bf16x8*)(convA2 + (3 * 64 + lane) * 8);
    bf16x8 sbf = *(const bf16x8*)(spB2 + lane * 8);
    bf16x8 ubf = *(const bf16x8*)(uB + lane * 8);
    bf16x8 vbf = *(const bf16x8*)(vB + lane * 8);

    int s0g = t >> 2, i0g = (t & 3) * 4;
    f32x4 m0 = (m0a + m0b) * idg, m1 = (m1a + m1b) * idg, m2 = (m2a + m2b) * idg;
    *(short4v*)&mt[s0g * 24 + i0g]         = pack4(m0);
    *(short4v*)&mt[(64 + s0g) * 24 + i0g]  = pack4(m1);
    if (t < 64) *(short4v*)&mt[(128 + s0g) * 24 + i0g] = pack4(m2);

    *(short4v*)&xs[(s0g + 2) * 24 + i0g]        = pack4(x0);
    *(short4v*)&xs[(64 + s0g + 2) * 24 + i0g]   = pack4(x1);
    if (t < 64) *(short4v*)&xs[(128 + s0g + 2) * 24 + i0g] = pack4(x2);
    if (t < 64) {                                      // conv halo zeros
        int r = t >> 4, i = t & 15;
        int row = (r < 2) ? r : 144 + r;               // 0,1,146,147
        xs[row * 24 + i] = 0;
    }
    if (t < SEQn) s_fbl[t] = fbl[t];
    if (t < 16) { s_bias[t] = biasf[t]; s_cs[t] = biasf[16 + t]; }
    __syncthreads();

    // ---- Stage A: U=x@H1, V=x@F1 -> uv; spatial GEMM -> accS regs ----
    __builtin_amdgcn_s_setprio(1);
    #pragma unroll
    for (int tt = 0; tt < 3; tt++) {
        if ((wave == 0) || (tt < 2)) {
            int mtt = ust_w + tt;
            int sl = mtt * 16 + ln;
            bf16x8 a = {0,0,0,0,0,0,0,0};
            if (q < 2) a = *(const bf16x8*)&xs[(sl + 2) * 24 + q * 8];
            f32x4 au = {0.f,0.f,0.f,0.f}, av = {0.f,0.f,0.f,0.f};
            au = MFMA(a, ubf, au);
            av = MFMA(a, vbf, av);
            *(short4v*)&uv[ln * 312 + mtt * 16 + q * 4]       = pack4(au);
            *(short4v*)&uv[ln * 312 + 144 + mtt * 16 + q * 4] = pack4(av);
        }
    }
    f32x4 accS0 = {0.f,0.f,0.f,0.f}, accS1 = accS0, accS2 = accS0;
    {
        int sl = (sst_w + 0) * 16 + ln;
        const unsigned short* ap = (q < 2) ? &mt[sl * 24 + (q & 1) * 8]
                                           : &xs[(sl + 2) * 24 + (q & 1) * 8];
        accS0 = MFMA(*(const bf16x8*)ap, sbf, accS0);
    }
    {
        int sl = (sst_w + 1) * 16 + ln;
        const unsigned short* ap = (q < 2) ? &mt[sl * 24 + (q & 1) * 8]
                                           : &xs[(sl + 2) * 24 + (q & 1) * 8];
        accS1 = MFMA(*(const bf16x8*)ap, sbf, accS1);
    }
    if (wave == 3) {
        int sl = (sst_w + 2) * 16 + ln;
        const unsigned short* ap = (q < 2) ? &mt[sl * 24 + (q & 1) * 8]
                                           : &xs[(sl + 2) * 24 + (q & 1) * 8];
        accS2 = MFMA(*(const bf16x8*)ap, sbf, accS2);
    }
    __builtin_amdgcn_s_setprio(0);
    __syncthreads();   // mt (mean) dead after this barrier

    // ---- Stage B compute: conv (4 MFMA) + feature K=288 (9 MFMA) -> regs ----
#define B_TILE(N0, ACC) { \
    int n0_t = (N0); int sl_t = n0_t * 16 + ln; \
    bf16x8 bfrag[9]; \
    _Pragma("unroll") \
    for (int kk = 0; kk < 9; kk++) \
        bfrag[kk] = *(const bf16x8*)(featB + ((kk * 9 + n0_t) * 64 + lane) * 8); \
    bf16x8 cb[4]; \
    _Pragma("unroll") \
    for (int kk = 0; kk < 4; kk++) { \
        int kkp = kk * 2 + (q >> 1); \
        int off = (kkp < 3) ? (kkp - 1) : (kkp - 5); \
        cb[kk] = *(const bf16x8*)&xs[(sl_t + 2 + off) * 24 + (q & 1) * 8]; } \
    f32x4 acc_ = {0.f,0.f,0.f,0.f}; \
    acc_ = MFMA(caf0, cb[0], acc_); \
    acc_ = MFMA(caf1, cb[1], acc_); \
    acc_ = MFMA(caf2, cb[2], acc_); \
    acc_ = MFMA(caf3, cb[3], acc_); \
    _Pragma("unroll") \
    for (int kk = 0; kk < 9; kk++) { \
        bf16x8 a_ = *(const bf16x8*)&uv[ln * 312 + kk * 32 + q * 8]; \
        acc_ = MFMA(a_, bfrag[kk], acc_); } \
    ACC = acc_; }

    __builtin_amdgcn_s_setprio(1);
    f32x4 accB0 = {0.f,0.f,0.f,0.f}, accB1 = accB0, accB2 = accB0;
    B_TILE(ust_w + 0, accB0)
    B_TILE(ust_w + 1, accB1)
    if (wave == 0) B_TILE(ust_w + 2, accB2)
#undef B_TILE
    __builtin_amdgcn_s_setprio(0);
    __syncthreads();   // xs, uv dead -> accF/accFS may now alias

    // ---- Single scatter phase: B (=) to accF, spatial (=) to accFS ----
    // B: C row = i' = q*4+r, col = s-in-tile = ln
    *(f32x4*)&accF[(((ust_w + 0) * 16 + ln) * 16) + q * 4] = accB0;
    *(f32x4*)&accF[(((ust_w + 1) * 16 + ln) * 16) + q * 4] = accB1;
    if (wave == 0)
        *(f32x4*)&accF[(((ust_w + 2) * 16 + ln) * 16) + q * 4] = accB2;
    // spatial: C row = s = q*4+r, col = i' = ln (full 144x16 coverage)
    #pragma unroll
    for (int r = 0; r < 4; r++)
        accFS[((sst_w + 0) * 16 + q * 4 + r) * 16 + ln] = accS0[r];
    #pragma unroll
    for (int r = 0; r < 4; r++)
        accFS[((sst_w + 1) * 16 + q * 4 + r) * 16 + ln] = accS1[r];
    if (wave == 3) {
        #pragma unroll
        for (int r = 0; r < 4; r++)
            accFS[((sst_w + 2) * 16 + q * 4 + r) * 16 + ln] = accS2[r];
    }
    __syncthreads();

    // ---- Epilogue: chunk-linear. accF + accFS + residual (regs) + bias ----
    f32x4* out4 = (f32x4*)(out + (size_t)bc * (SEQn * INVn));
    int i0 = (t & 3) * 4;
    f32x4 bias4 = *(const f32x4*)&s_bias[i0];
    f32x4 cs4   = *(const f32x4*)&s_cs[i0];
    {
        f32x4 a = *(const f32x4*)&accF[4 * t];
        f32x4 s = *(const f32x4*)&accFS[4 * t];
        out4[t] = a + s + x0 + bias4 + s_fbl[t >> 2] * cs4;
    }
    {
        f32x4 a = *(const f32x4*)&accF[4 * (t + 256)];
        f32x4 s = *(const f32x4*)&accFS[4 * (t + 256)];
        out4[t + 256] = a + s + x1 + bias4 + s_fbl[(t + 256) >> 2] * cs4;
    }
    if (t < 64) {
        f32x4 a = *(const f32x4*)&accF[4 * (t + 512)];
        f32x4 s = *(const f32x4*)&accFS[4 * (t + 512)];
        out4[t + 512] = a + s + x2 + bias4 + s_fbl[(t + 512) >> 2] * cs4;
    }
}

extern "C" void kernel_launch(void* const* d_in, const int* in_sizes, int n_in,
                              void* d_out, int out_size, void* d_ws, size_t ws_size,
                              hipStream_t stream)
{
    const float* src = (const float*)d_in[0];
    const int* ge = (const int*)d_in[1];
    const int* fe = (const int*)d_in[2];
    const float* Wl  = (const float*)d_in[3];
    const float* blp = (const float*)d_in[4];
    const float* Wr  = (const float*)d_in[5];
    const float* fWl = (const float*)d_in[6];
    const float* fbl = (const float*)d_in[7];
    const float* fWr = (const float*)d_in[8];
    const float* w1  = (const float*)d_in[9];
    const float* w2  = (const float*)d_in[10];
    const float* fcw = (const float*)d_in[11];
    const float* fcb = (const float*)d_in[12];
    float* out = (float*)d_out;
    int* ws = (int*)d_ws;

    hipLaunchKernelGGL(prep_kernel, dim3(84), dim3(256), 0, stream,
                       ge, fe, Wl, Wr, fWl, fWr, w1, w2, fcw, blp, fcb, ws);
    hipLaunchKernelGGL(fused_kernel, dim3(BZn * CAPn), dim3(256), 0, stream,
                       src, fbl, ws, out);
}